// Round 11
// baseline (631.549 us; speedup 1.0000x reference)
//
#include <hip/hip_runtime.h>
#include <math.h>

#define T_TOKENS 32768
#define HIDDEN   4096
#define NEXP     128
#define BK       32
#define NSTAGE   (HIDDEN / BK)            // 128
#define SC_STRIDE 129
#define B_CHUNK_SH 12288                  // shorts per stage in w image (24 KB)
#define WS_BYTES ((size_t)NSTAGE * B_CHUNK_SH * 2)   // 3 MiB

typedef short bf16x8 __attribute__((ext_vector_type(8)));
typedef float f32x4  __attribute__((ext_vector_type(4)));

__device__ __forceinline__ unsigned short f2bf(float f) {
    unsigned u = __float_as_uint(f);
    u += 0x7FFF + ((u >> 16) & 1);          // round-to-nearest-even
    return (unsigned short)(u >> 16);
}
__device__ __forceinline__ float bf2f(unsigned short h) {
    return __uint_as_float(((unsigned)h) << 16);
}
// 3-term bf16 cascade: x = b0 + b1 + b2 + delta, |delta| <= 2^-27 |x|
__device__ __forceinline__ void split3(float x, unsigned short& b0,
                                       unsigned short& b1, unsigned short& b2) {
    b0 = f2bf(x);
    float r1 = x - bf2f(b0);                // exact (Sterbenz)
    b1 = f2bf(r1);
    float r2 = r1 - bf2f(b1);               // exact
    b2 = f2bf(r2);
}

// ---- kernel 1: split w into 3 bf16 planes, fragment-major (IDENTICAL image
// to rounds 5-10): stage s, plane p, tile t, lane l holds
// w[t*16+(l&15)][s*32+(l>>4)*8+j] at ws16[((s*24 + p*8 + t)*64 + l)*8].
__global__ __launch_bounds__(256) void presplit_w(
    const float* __restrict__ w, short* __restrict__ ws16)
{
    const int g = blockIdx.x * 256 + threadIdx.x;    // 65536 total
    const int l = g & 63;
    const int t = (g >> 6) & 7;
    const int s = g >> 9;                            // 0..127
    const int e  = t * 16 + (l & 15);
    const int kb = s * BK + ((l >> 4) & 3) * 8;
    const float* src = w + (size_t)e * HIDDEN + kb;
    float4 v0 = *(const float4*)(src);
    float4 v1 = *(const float4*)(src + 4);
    float vv[8] = {v0.x, v0.y, v0.z, v0.w, v1.x, v1.y, v1.z, v1.w};
    unsigned short h0[8], h1[8], h2[8];
#pragma unroll
    for (int j = 0; j < 8; ++j) split3(vv[j], h0[j], h1[j], h2[j]);
    const size_t base = ((size_t)s * 24 + t) * 64 + l;
    bf16x8 o0 = {(short)h0[0],(short)h0[1],(short)h0[2],(short)h0[3],
                 (short)h0[4],(short)h0[5],(short)h0[6],(short)h0[7]};
    bf16x8 o1 = {(short)h1[0],(short)h1[1],(short)h1[2],(short)h1[3],
                 (short)h1[4],(short)h1[5],(short)h1[6],(short)h1[7]};
    bf16x8 o2 = {(short)h2[0],(short)h2[1],(short)h2[2],(short)h2[3],
                 (short)h2[4],(short)h2[5],(short)h2[6],(short)h2[7]};
    *(bf16x8*)(ws16 + (base + 0 * 8 * 64) * 8) = o0;
    *(bf16x8*)(ws16 + (base + 1 * 8 * 64) * 8) = o1;
    *(bf16x8*)(ws16 + (base + 2 * 8 * 64) * 8) = o2;
}

// 256 threads = 4 waves; each wave INDEPENDENTLY owns 16 tokens x 128 experts.
// A: built in registers from the wave's own x rows (read exactly once).
// B: per-wave global->VGPR from the presplit image (L1/L2-served).
// NO barriers, NO LDS, NO inline asm in the main loop -> compiler free to
// software-pipeline loads across stages. Products / order / K=128 fp64 fold
// are bit-identical to rounds 5-10.
__global__ __launch_bounds__(256, 2) void glm4_router_mfma(
    const float* __restrict__ x, const short* __restrict__ wsplit,
    const float* __restrict__ bias, float* __restrict__ out)
{
    __shared__ float sc[64 * SC_STRIDE];    // 33 KB, epilogue/routing only

    const int tid  = threadIdx.x;
    const int wid  = tid >> 6;              // 0..3
    const int lane = tid & 63;
    const int tok_blk  = blockIdx.x * 64;
    const int tok_wave = tok_blk + wid * 16;

    // this lane's x slice: row tok_wave + (lane&15), k-octet (lane>>4)*8
    const float* xr = x + (size_t)(tok_wave + (lane & 15)) * HIDDEN
                        + ((lane >> 4) & 3) * 8;
    // B fragment base for this lane
    const short* wf = wsplit + (size_t)lane * 8;

    f32x4 acc[8];           // 8 expert-tiles, fp32, zeroed every K=128
    double accd[8][4];      // fp64 running sum
#pragma unroll
    for (int t = 0; t < 8; ++t) {
        acc[t] = (f32x4){0.f, 0.f, 0.f, 0.f};
#pragma unroll
        for (int v = 0; v < 4; ++v) accd[t][v] = 0.0;
    }

    // stage-0 x
    float4 xc0 = *(const float4*)(xr);
    float4 xc1 = *(const float4*)(xr + 4);

#pragma unroll 4
    for (int s = 0; s < NSTAGE; ++s) {
        // prefetch next-stage x (stays in flight; no barrier ever drains it)
        float4 xn0 = xc0, xn1 = xc1;
        if (s + 1 < NSTAGE) {
            const float* nx = xr + (size_t)(s + 1) * BK;
            xn0 = *(const float4*)(nx);
            xn1 = *(const float4*)(nx + 4);
        }

        // split this lane's 8 x-values -> 3 bf16x8 A fragments (in registers)
        float vv[8] = {xc0.x, xc0.y, xc0.z, xc0.w, xc1.x, xc1.y, xc1.z, xc1.w};
        unsigned short h0[8], h1[8], h2[8];
#pragma unroll
        for (int j = 0; j < 8; ++j) split3(vv[j], h0[j], h1[j], h2[j]);
        bf16x8 a0 = {(short)h0[0],(short)h0[1],(short)h0[2],(short)h0[3],
                     (short)h0[4],(short)h0[5],(short)h0[6],(short)h0[7]};
        bf16x8 a1 = {(short)h1[0],(short)h1[1],(short)h1[2],(short)h1[3],
                     (short)h1[4],(short)h1[5],(short)h1[6],(short)h1[7]};
        bf16x8 a2 = {(short)h2[0],(short)h2[1],(short)h2[2],(short)h2[3],
                     (short)h2[4],(short)h2[5],(short)h2[6],(short)h2[7]};

        const short* wstage = wf + (size_t)s * B_CHUNK_SH;
#pragma unroll
        for (int t = 0; t < 8; ++t) {
            bf16x8 b0 = *(const bf16x8*)(wstage + (0 * 8 + t) * 512);
            bf16x8 b1 = *(const bf16x8*)(wstage + (1 * 8 + t) * 512);
            bf16x8 b2 = *(const bf16x8*)(wstage + (2 * 8 + t) * 512);
            acc[t] = __builtin_amdgcn_mfma_f32_16x16x32_bf16(a0, b0, acc[t], 0, 0, 0);
            acc[t] = __builtin_amdgcn_mfma_f32_16x16x32_bf16(a0, b1, acc[t], 0, 0, 0);
            acc[t] = __builtin_amdgcn_mfma_f32_16x16x32_bf16(a1, b0, acc[t], 0, 0, 0);
            acc[t] = __builtin_amdgcn_mfma_f32_16x16x32_bf16(a0, b2, acc[t], 0, 0, 0);
            acc[t] = __builtin_amdgcn_mfma_f32_16x16x32_bf16(a2, b0, acc[t], 0, 0, 0);
            acc[t] = __builtin_amdgcn_mfma_f32_16x16x32_bf16(a1, b1, acc[t], 0, 0, 0);
        }

        // fold into fp64 every K=128 (caps fp32 C-accum random walk)
        if ((s & 3) == 3) {
#pragma unroll
            for (int t = 0; t < 8; ++t) {
#pragma unroll
                for (int v = 0; v < 4; ++v) accd[t][v] += (double)acc[t][v];
                acc[t] = (f32x4){0.f, 0.f, 0.f, 0.f};
            }
        }
        xc0 = xn0; xc1 = xn1;
    }

    // ---- epilogue: logits -> biased scores into LDS (fp32) ----
    // C layout 16x16x32: token = (lane>>4)*4 + v, expert = t*16 + (lane&15)
#pragma unroll
    for (int t = 0; t < 8; ++t) {
#pragma unroll
        for (int v = 0; v < 4; ++v) {
            const int tokl = wid * 16 + (lane >> 4) * 4 + v;
            const int e    = t * 16 + (lane & 15);
            const float lg = (float)accd[t][v];
            const float sg = (float)(1.0 / (1.0 + exp(-(double)lg)));
            sc[tokl * SC_STRIDE + e] = sg + bias[e];
        }
    }
    __syncthreads();

    // ---- routing: one lane per token (wave 0) — verified logic ----
    if (tid < 64) {
        const float* scp = sc + tid * SC_STRIDE;

        float gsc[8];
#pragma unroll
        for (int g = 0; g < 8; ++g) {
            float m1 = -1e30f, m2 = -1e30f;
#pragma unroll
            for (int j = 0; j < 16; ++j) {
                const float v = scp[g * 16 + j];
                if (v > m1) { m2 = m1; m1 = v; }
                else if (v > m2) { m2 = v; }
            }
            gsc[g] = m1 + m2;
        }

        unsigned gmask = 0;
#pragma unroll
        for (int p = 0; p < 4; ++p) {
            float best = -1e30f; int bi = 0;
#pragma unroll
            for (int g = 0; g < 8; ++g) {
                const bool taken = (gmask >> g) & 1u;
                if (!taken && gsc[g] > best) { best = gsc[g]; bi = g; }
            }
            gmask |= 1u << bi;
        }

        unsigned long long chosen0 = 0ull, chosen1 = 0ull;
        int   idxs[8];
        float wts[8];
#pragma unroll
        for (int p = 0; p < 8; ++p) {
            float best = -1e30f; int bi = 0;
            for (int e = 0; e < NEXP; ++e) {
                const bool sel = (gmask >> (e >> 4)) & 1u;
                const float v = sel ? scp[e] : 0.0f;
                const bool ch = (e < 64) ? ((chosen0 >> e) & 1ull)
                                         : ((chosen1 >> (e - 64)) & 1ull);
                if (!ch && v > best) { best = v; bi = e; }
            }
            if (bi < 64) chosen0 |= 1ull << bi; else chosen1 |= 1ull << (bi - 64);
            idxs[p] = bi;
            wts[p] = scp[bi] - bias[bi];   // raw sigmoid, ~1e-7 error
        }

        float denom = 0.0f;
#pragma unroll
        for (int p = 0; p < 8; ++p) denom += wts[p];
        denom += 1e-20f;

        const size_t row = (size_t)(tok_blk + tid) * 8;
        float* outI = out;
        float* outW = out + (size_t)T_TOKENS * 8;
#pragma unroll
        for (int p = 0; p < 8; ++p) {
            outI[row + p] = (float)idxs[p];
            outW[row + p] = wts[p] / denom;
        }
    }
}

extern "C" void kernel_launch(void* const* d_in, const int* in_sizes, int n_in,
                              void* d_out, int out_size, void* d_ws, size_t ws_size,
                              hipStream_t stream) {
    const float* x    = (const float*)d_in[0];  // [32768, 4096]
    const float* w    = (const float*)d_in[1];  // [128, 4096]
    const float* bias = (const float*)d_in[2];  // [128]
    float* out = (float*)d_out;                 // [idx-as-float | weights]
    short* ws16 = (short*)d_ws;                 // 3 MiB pre-split w image

    presplit_w<<<dim3(NSTAGE * 8 * 64 / 256), 256, 0, stream>>>(w, ws16);
    glm4_router_mfma<<<dim3(T_TOKENS / 64), 256, 0, stream>>>(x, ws16, bias, out);
}

// Round 13
// 274.482 us; speedup vs baseline: 2.3009x; 2.3009x over previous
//
#include <hip/hip_runtime.h>
#include <math.h>

#define T_TOKENS 32768
#define HIDDEN   4096
#define NEXP     128
#define TM       64
#define BK       32
#define NSTAGE   (HIDDEN / BK)            // 128

// LDS (shorts): [Abuf0 12KB][Abuf1 12KB][Bbuf0 24KB][Bbuf1 24KB] = 72 KiB
#define A_BUF_SH      6144
#define B_BASE_SH     (2 * A_BUF_SH)      // 12288
#define B_BUF_SH      12288
#define LDS_SHORTS    (B_BASE_SH + 2 * B_BUF_SH)   // 36864 shorts = 72 KiB
#define B_BASE_BYTES  (B_BASE_SH * 2)
#define B_BUF_BYTES   (B_BUF_SH * 2)
#define A_PLANE_SH    2048
#define B_PLANE_SH    4096
#define SC_STRIDE     129
#define B_CHUNK_BYTES B_BUF_BYTES
#define WS_BYTES ((size_t)NSTAGE * B_CHUNK_BYTES)  // 3 MiB

typedef short bf16x8 __attribute__((ext_vector_type(8)));
typedef short bf16x4 __attribute__((ext_vector_type(4)));
typedef float f32x4  __attribute__((ext_vector_type(4)));

__device__ __forceinline__ unsigned short f2bf(float f) {
    unsigned u = __float_as_uint(f);
    u += 0x7FFF + ((u >> 16) & 1);          // round-to-nearest-even
    return (unsigned short)(u >> 16);
}
__device__ __forceinline__ float bf2f(unsigned short h) {
    return __uint_as_float(((unsigned)h) << 16);
}
// 3-term bf16 cascade: x = b0 + b1 + b2 + delta, |delta| <= 2^-27 |x|
__device__ __forceinline__ void split3(float x, unsigned short& b0,
                                       unsigned short& b1, unsigned short& b2) {
    b0 = f2bf(x);
    float r1 = x - bf2f(b0);                // exact (Sterbenz)
    b1 = f2bf(r1);
    float r2 = r1 - bf2f(b1);               // exact
    b2 = f2bf(r2);
}

// ---- kernel 1: split w into 3 bf16 planes, fragment-major (IDENTICAL image
// to rounds 5-10): stage s, plane p, tile t, lane l holds
// w[t*16+(l&15)][s*32+(l>>4)*8+j] at ws16[((s*24 + p*8 + t)*64 + l)*8].
__global__ __launch_bounds__(256) void presplit_w(
    const float* __restrict__ w, short* __restrict__ ws16)
{
    const int g = blockIdx.x * 256 + threadIdx.x;    // 65536 total
    const int l = g & 63;
    const int t = (g >> 6) & 7;
    const int s = g >> 9;                            // 0..127
    const int e  = t * 16 + (l & 15);
    const int kb = s * BK + ((l >> 4) & 3) * 8;
    const float* src = w + (size_t)e * HIDDEN + kb;
    float4 v0 = *(const float4*)(src);
    float4 v1 = *(const float4*)(src + 4);
    float vv[8] = {v0.x, v0.y, v0.z, v0.w, v1.x, v1.y, v1.z, v1.w};
    unsigned short h0[8], h1[8], h2[8];
#pragma unroll
    for (int j = 0; j < 8; ++j) split3(vv[j], h0[j], h1[j], h2[j]);
    const size_t base = ((size_t)s * 24 + t) * 64 + l;
    bf16x8 o0 = {(short)h0[0],(short)h0[1],(short)h0[2],(short)h0[3],
                 (short)h0[4],(short)h0[5],(short)h0[6],(short)h0[7]};
    bf16x8 o1 = {(short)h1[0],(short)h1[1],(short)h1[2],(short)h1[3],
                 (short)h1[4],(short)h1[5],(short)h1[6],(short)h1[7]};
    bf16x8 o2 = {(short)h2[0],(short)h2[1],(short)h2[2],(short)h2[3],
                 (short)h2[4],(short)h2[5],(short)h2[6],(short)h2[7]};
    *(bf16x8*)(ws16 + (base + 0 * 8 * 64) * 8) = o0;
    *(bf16x8*)(ws16 + (base + 1 * 8 * 64) * 8) = o1;
    *(bf16x8*)(ws16 + (base + 2 * 8 * 64) * 8) = o2;
}

// 512 threads = 8 waves; wave owns 32 tok x 32 exp (2x2 of 16x16 tiles).
// R9's verified sync (one __syncthreads per stage: full vmcnt/lgkm drain +
// barrier) with R12's instruction INTERLEAVE only: SPLIT_A's VALU+ds_write
// sits between the two 12-MFMA column clusters; col-1 B reads hide under
// col-0 MFMA. No hand-rolled waitcnt anywhere.
__global__ __launch_bounds__(512, 4) void glm4_router_mfma(
    const float* __restrict__ x, const short* __restrict__ wsplit,
    const float* __restrict__ bias, float* __restrict__ out)
{
    __shared__ __align__(16) short lds[LDS_SHORTS];

    const int tid  = threadIdx.x;
    const int wid  = tid >> 6;
    const int lane = tid & 63;
    const int rt_base = (wid & 1) * 2;      // row-tile base: 0 or 2
    const int ct_base = (wid >> 1) * 2;     // col-tile base: 0,2,4,6
    const int tok_base = blockIdx.x * TM;

    // A staging: thread tid b64-writes shorts [tid*4..tid*4+3] of each plane.
    // Fragment image: t=tid>>7, l=(tid>>1)&63, j4=(tid&1)*4;
    // row = t*16+(l&15), k = s*32 + ((l>>4)&3)*8 + j4.
    const int al = (tid >> 1) & 63;
    const int at = tid >> 7;
    const int arow = at * 16 + (al & 15);
    const int akoff = ((al >> 4) & 3) * 8 + (tid & 1) * 4;
    const float* xsrc = x + (size_t)(tok_base + arow) * HIDDEN + akoff;
    const int awr = tid * 4;                // shorts, within a plane

    f32x4 acc[2][2];        // all 6 split-products, zeroed every K=128
    double accd[2][2][4];   // fp64 running sum
#pragma unroll
    for (int r = 0; r < 2; ++r)
#pragma unroll
        for (int c = 0; c < 2; ++c) {
            acc[r][c] = (f32x4){0.f, 0.f, 0.f, 0.f};
#pragma unroll
            for (int v = 0; v < 4; ++v) accd[r][c][v] = 0.0;
        }

#define GLDS_B(S, BUF) do {                                                    \
    const char* gsrc_ = (const char*)wsplit + (size_t)(S) * B_CHUNK_BYTES + tid * 16; \
    char* ldst_ = (char*)lds + B_BASE_BYTES + (BUF) * B_BUF_BYTES + tid * 16;  \
    __builtin_amdgcn_global_load_lds(                                          \
        (const __attribute__((address_space(1))) unsigned*)(gsrc_),            \
        (__attribute__((address_space(3))) unsigned*)(ldst_), 16, 0, 0);       \
    __builtin_amdgcn_global_load_lds(                                          \
        (const __attribute__((address_space(1))) unsigned*)(gsrc_ + 8192),     \
        (__attribute__((address_space(3))) unsigned*)(ldst_ + 8192), 16, 0, 0);\
    __builtin_amdgcn_global_load_lds(                                          \
        (const __attribute__((address_space(1))) unsigned*)(gsrc_ + 16384),    \
        (__attribute__((address_space(3))) unsigned*)(ldst_ + 16384), 16, 0, 0);\
} while (0)

#define SPLIT_A(XV, BUF) do {                                                  \
    unsigned short h0_[4], h1_[4], h2_[4];                                     \
    split3((XV).x, h0_[0], h1_[0], h2_[0]);                                    \
    split3((XV).y, h0_[1], h1_[1], h2_[1]);                                    \
    split3((XV).z, h0_[2], h1_[2], h2_[2]);                                    \
    split3((XV).w, h0_[3], h1_[3], h2_[3]);                                    \
    short* ab_ = &lds[(BUF) * A_BUF_SH + awr];                                 \
    *(bf16x4*)(ab_ + 0 * A_PLANE_SH) =                                         \
        (bf16x4){(short)h0_[0], (short)h0_[1], (short)h0_[2], (short)h0_[3]};  \
    *(bf16x4*)(ab_ + 1 * A_PLANE_SH) =                                         \
        (bf16x4){(short)h1_[0], (short)h1_[1], (short)h1_[2], (short)h1_[3]};  \
    *(bf16x4*)(ab_ + 2 * A_PLANE_SH) =                                         \
        (bf16x4){(short)h2_[0], (short)h2_[1], (short)h2_[2], (short)h2_[3]};  \
} while (0)

    // 12 MFMA for one column C (per-acc product order identical to R5-R11:
    // a0b0, a0b1, a1b0, a0b2, a2b0, a1b1)
#define MFMA_COL(C, B0_, B1_, B2_) do {                                        \
    _Pragma("unroll")                                                          \
    for (int r = 0; r < 2; ++r) {                                              \
        acc[r][C] = __builtin_amdgcn_mfma_f32_16x16x32_bf16(Af[0][r], B0_, acc[r][C], 0, 0, 0); \
        acc[r][C] = __builtin_amdgcn_mfma_f32_16x16x32_bf16(Af[0][r], B1_, acc[r][C], 0, 0, 0); \
        acc[r][C] = __builtin_amdgcn_mfma_f32_16x16x32_bf16(Af[1][r], B0_, acc[r][C], 0, 0, 0); \
        acc[r][C] = __builtin_amdgcn_mfma_f32_16x16x32_bf16(Af[0][r], B2_, acc[r][C], 0, 0, 0); \
        acc[r][C] = __builtin_amdgcn_mfma_f32_16x16x32_bf16(Af[2][r], B0_, acc[r][C], 0, 0, 0); \
        acc[r][C] = __builtin_amdgcn_mfma_f32_16x16x32_bf16(Af[1][r], B1_, acc[r][C], 0, 0, 0); \
    }                                                                          \
} while (0)

#define BODY(S, BUF, XC, XL) do {                                              \
    GLDS_B((S) + 1, (BUF) ^ 1);                                                \
    {                                                                          \
        int s2_ = (S) + 2; if (s2_ > NSTAGE - 1) s2_ = NSTAGE - 1;             \
        XL = *(const float4*)(xsrc + (size_t)s2_ * BK);                        \
    }                                                                          \
    bf16x8 Af[3][2];                                                           \
    _Pragma("unroll")                                                          \
    for (int p = 0; p < 3; ++p)                                                \
        _Pragma("unroll")                                                      \
        for (int r = 0; r < 2; ++r)                                            \
            Af[p][r] = *(const bf16x8*)(&lds[(BUF) * A_BUF_SH + p * A_PLANE_SH \
                                             + ((rt_base + r) * 64 + lane) * 8]); \
    {                                                                          \
        bf16x8 Bc0 = *(const bf16x8*)(&lds[B_BASE_SH + (BUF) * B_BUF_SH        \
                          + 0 * B_PLANE_SH + ((ct_base + 0) * 64 + lane) * 8]);\
        bf16x8 Bc1 = *(const bf16x8*)(&lds[B_BASE_SH + (BUF) * B_BUF_SH        \
                          + 1 * B_PLANE_SH + ((ct_base + 0) * 64 + lane) * 8]);\
        bf16x8 Bc2 = *(const bf16x8*)(&lds[B_BASE_SH + (BUF) * B_BUF_SH        \
                          + 2 * B_PLANE_SH + ((ct_base + 0) * 64 + lane) * 8]);\
        __builtin_amdgcn_s_setprio(1);                                         \
        MFMA_COL(0, Bc0, Bc1, Bc2);                                            \
        __builtin_amdgcn_s_setprio(0);                                         \
    }                                                                          \
    SPLIT_A(XC, (BUF) ^ 1);   /* VALU + ds_write between MFMA clusters */      \
    {                                                                          \
        bf16x8 Bc0 = *(const bf16x8*)(&lds[B_BASE_SH + (BUF) * B_BUF_SH        \
                          + 0 * B_PLANE_SH + ((ct_base + 1) * 64 + lane) * 8]);\
        bf16x8 Bc1 = *(const bf16x8*)(&lds[B_BASE_SH + (BUF) * B_BUF_SH        \
                          + 1 * B_PLANE_SH + ((ct_base + 1) * 64 + lane) * 8]);\
        bf16x8 Bc2 = *(const bf16x8*)(&lds[B_BASE_SH + (BUF) * B_BUF_SH        \
                          + 2 * B_PLANE_SH + ((ct_base + 1) * 64 + lane) * 8]);\
        __builtin_amdgcn_s_setprio(1);                                         \
        MFMA_COL(1, Bc0, Bc1, Bc2);                                            \
        __builtin_amdgcn_s_setprio(0);                                         \
    }                                                                          \
    if (((S) & 3) == 3) {                                                      \
        _Pragma("unroll")                                                      \
        for (int r = 0; r < 2; ++r)                                            \
            _Pragma("unroll")                                                  \
            for (int c = 0; c < 2; ++c) {                                      \
                _Pragma("unroll")                                              \
                for (int v = 0; v < 4; ++v) accd[r][c][v] += (double)acc[r][c][v]; \
                acc[r][c] = (f32x4){0.f, 0.f, 0.f, 0.f};                       \
            }                                                                  \
    }                                                                          \
    __syncthreads();   /* full drain + barrier: verified-correct handoff */    \
} while (0)

    // prologue: fill buf0 with stage 0 (B glds + A split), prefetch x[1]
    float4 xA, xB;
    {
        float4 x0v = *(const float4*)(xsrc);
        GLDS_B(0, 0);
        xA = *(const float4*)(xsrc + BK);   // x[1]
        SPLIT_A(x0v, 0);
    }
    __syncthreads();

    for (int s = 0; s < NSTAGE - 2; s += 2) {
        BODY(s, 0, xA, xB);
        BODY(s + 1, 1, xB, xA);
    }
    BODY(NSTAGE - 2, 0, xA, xB);

    // tail: stage 127 from buf1 (fully staged; drained by the last barrier)
    {
        bf16x8 Af[3][2];
#pragma unroll
        for (int p = 0; p < 3; ++p)
#pragma unroll
            for (int r = 0; r < 2; ++r)
                Af[p][r] = *(const bf16x8*)(&lds[1 * A_BUF_SH + p * A_PLANE_SH
                                                 + ((rt_base + r) * 64 + lane) * 8]);
#pragma unroll
        for (int c = 0; c < 2; ++c) {
            bf16x8 Bc0 = *(const bf16x8*)(&lds[B_BASE_SH + 1 * B_BUF_SH
                              + 0 * B_PLANE_SH + ((ct_base + c) * 64 + lane) * 8]);
            bf16x8 Bc1 = *(const bf16x8*)(&lds[B_BASE_SH + 1 * B_BUF_SH
                              + 1 * B_PLANE_SH + ((ct_base + c) * 64 + lane) * 8]);
            bf16x8 Bc2 = *(const bf16x8*)(&lds[B_BASE_SH + 1 * B_BUF_SH
                              + 2 * B_PLANE_SH + ((ct_base + c) * 64 + lane) * 8]);
#pragma unroll
            for (int r = 0; r < 2; ++r) {
                acc[r][c] = __builtin_amdgcn_mfma_f32_16x16x32_bf16(Af[0][r], Bc0, acc[r][c], 0, 0, 0);
                acc[r][c] = __builtin_amdgcn_mfma_f32_16x16x32_bf16(Af[0][r], Bc1, acc[r][c], 0, 0, 0);
                acc[r][c] = __builtin_amdgcn_mfma_f32_16x16x32_bf16(Af[1][r], Bc0, acc[r][c], 0, 0, 0);
                acc[r][c] = __builtin_amdgcn_mfma_f32_16x16x32_bf16(Af[0][r], Bc2, acc[r][c], 0, 0, 0);
                acc[r][c] = __builtin_amdgcn_mfma_f32_16x16x32_bf16(Af[2][r], Bc0, acc[r][c], 0, 0, 0);
                acc[r][c] = __builtin_amdgcn_mfma_f32_16x16x32_bf16(Af[1][r], Bc1, acc[r][c], 0, 0, 0);
            }
        }
        // final fold (S=127 -> (S&3)==3)
#pragma unroll
        for (int r = 0; r < 2; ++r)
#pragma unroll
            for (int c = 0; c < 2; ++c)
#pragma unroll
                for (int v = 0; v < 4; ++v) accd[r][c][v] += (double)acc[r][c][v];
    }

    // ---- epilogue: logits -> biased scores into LDS overlay (fp32) ----
    __syncthreads();
    float* sc = (float*)lds;                       // [64][129] = 33 KB
#pragma unroll
    for (int r = 0; r < 2; ++r)
#pragma unroll
        for (int c = 0; c < 2; ++c) {
#pragma unroll
            for (int v = 0; v < 4; ++v) {
                const int tokl = (rt_base + r) * 16 + (lane >> 4) * 4 + v;
                const int e    = (ct_base + c) * 16 + (lane & 15);
                const float lg = (float)accd[r][c][v];
                const float sg = (float)(1.0 / (1.0 + exp(-(double)lg)));
                sc[tokl * SC_STRIDE + e] = sg + bias[e];
            }
        }
    __syncthreads();

    // ---- routing: one lane per token (wave 0) — verified logic ----
    if (tid < TM) {
        const float* scp = sc + tid * SC_STRIDE;

        float gsc[8];
#pragma unroll
        for (int g = 0; g < 8; ++g) {
            float m1 = -1e30f, m2 = -1e30f;
#pragma unroll
            for (int j = 0; j < 16; ++j) {
                const float v = scp[g * 16 + j];
                if (v > m1) { m2 = m1; m1 = v; }
                else if (v > m2) { m2 = v; }
            }
            gsc[g] = m1 + m2;
        }

        unsigned gmask = 0;
#pragma unroll
        for (int p = 0; p < 4; ++p) {
            float best = -1e30f; int bi = 0;
#pragma unroll
            for (int g = 0; g < 8; ++g) {
                const bool taken = (gmask >> g) & 1u;
                if (!taken && gsc[g] > best) { best = gsc[g]; bi = g; }
            }
            gmask |= 1u << bi;
        }

        unsigned long long chosen0 = 0ull, chosen1 = 0ull;
        int   idxs[8];
        float wts[8];
#pragma unroll
        for (int p = 0; p < 8; ++p) {
            float best = -1e30f; int bi = 0;
            for (int e = 0; e < NEXP; ++e) {
                const bool sel = (gmask >> (e >> 4)) & 1u;
                const float v = sel ? scp[e] : 0.0f;
                const bool ch = (e < 64) ? ((chosen0 >> e) & 1ull)
                                         : ((chosen1 >> (e - 64)) & 1ull);
                if (!ch && v > best) { best = v; bi = e; }
            }
            if (bi < 64) chosen0 |= 1ull << bi; else chosen1 |= 1ull << (bi - 64);
            idxs[p] = bi;
            wts[p] = scp[bi] - bias[bi];   // raw sigmoid, ~1e-7 error
        }

        float denom = 0.0f;
#pragma unroll
        for (int p = 0; p < 8; ++p) denom += wts[p];
        denom += 1e-20f;

        const size_t row = (size_t)(tok_base + tid) * 8;
        float* outI = out;
        float* outW = out + (size_t)T_TOKENS * 8;
#pragma unroll
        for (int p = 0; p < 8; ++p) {
            outI[row + p] = (float)idxs[p];
            outW[row + p] = wts[p] / denom;
        }
    }
}

extern "C" void kernel_launch(void* const* d_in, const int* in_sizes, int n_in,
                              void* d_out, int out_size, void* d_ws, size_t ws_size,
                              hipStream_t stream) {
    const float* x    = (const float*)d_in[0];  // [32768, 4096]
    const float* w    = (const float*)d_in[1];  // [128, 4096]
    const float* bias = (const float*)d_in[2];  // [128]
    float* out = (float*)d_out;                 // [idx-as-float | weights]
    short* ws16 = (short*)d_ws;                 // 3 MiB pre-split w image

    presplit_w<<<dim3(NSTAGE * 8 * 64 / 256), 256, 0, stream>>>(w, ws16);
    glm4_router_mfma<<<dim3(T_TOKENS / TM), 512, 0, stream>>>(x, ws16, bias, out);
}